// Round 2
// 203.070 us; speedup vs baseline: 1.0128x; 1.0128x over previous
//
#include <hip/hip_runtime.h>
#include <math.h>

#define NB 8
#define NN 16384
#define NT 8
#define ND 256
#define NEG_FILL_F (-1e20f)

// monotonic float->uint key: order(key) == order(float), ascending
__device__ __forceinline__ unsigned fkey(float s){
  unsigned u = __float_as_uint(s);
  return (u & 0x80000000u) ? ~u : (u | 0x80000000u);
}
__device__ __forceinline__ float fkey_inv(unsigned k){
  unsigned u = (k & 0x80000000u) ? (k ^ 0x80000000u) : ~k;
  return __uint_as_float(u);
}

__device__ __forceinline__ float prob_of(const float4 x, const float4 y){
  float m = fmaxf(fmaxf(fmaxf(x.x,x.y),fmaxf(x.z,x.w)),
                  fmaxf(fmaxf(y.x,y.y),fmaxf(y.z,y.w)));
  float e0=expf(x.x-m), e1=expf(x.y-m), e2=expf(x.z-m), e3=expf(x.w-m);
  float e4=expf(y.x-m), e5=expf(y.y-m), e6=expf(y.z-m), e7=expf(y.w-m);
  float sum = ((((((e0+e1)+e2)+e3)+e4)+e5)+e6)+e7;
  float pm = fmaxf(fmaxf(fmaxf(e1,e2),fmaxf(e3,e4)),fmaxf(fmaxf(e5,e6),e7));
  return pm/sum;   // max_{t>=1} softmax[t] == max_{t>=1} e_t / sum (division monotone)
}

// keys[b,n] = fkey( span_mask ? max(prob_a, prob_b) : NEG_FILL )
// writes this block's high-byte histogram to its private gpart slot (no atomics, no init)
__global__ void k_scores(const float* __restrict__ sa, const float* __restrict__ sb,
                         const int* __restrict__ mask, unsigned* __restrict__ outk,
                         int* __restrict__ gpart){
  __shared__ int lh[256];
  const int t = threadIdx.x;
  lh[t] = 0;
  __syncthreads();
  int i = blockIdx.x*256 + t;            // 256 threads/block, 64 blocks per batch
  const float4* pa = (const float4*)(sa + (size_t)i*NT);
  const float4* pb = (const float4*)(sb + (size_t)i*NT);
  float4 a0=pa[0], a1=pa[1], b0=pb[0], b1=pb[1];
  float p = fmaxf(prob_of(a0,a1), prob_of(b0,b1));
  unsigned k = fkey(mask[i] ? p : NEG_FILL_F);
  outk[i] = k;
  atomicAdd(&lh[k>>24], 1);
  __syncthreads();
  gpart[blockIdx.x*256 + t] = lh[t];     // full 256-bin partial, plain store
}

// 32-bit exclusive scan over 1024 threads (thread order == span order)
__device__ int block_scan_excl(int v, int* lds, int tid){
  __syncthreads();   // protect lds reuse across calls
  int lane = tid & 63, wave = tid >> 6;
  int x = v;
  #pragma unroll
  for (int off=1; off<64; off<<=1){
    int y = __shfl_up(x, off, 64);
    if (lane >= off) x += y;
  }
  if (lane == 63) lds[wave] = x;       // wave totals
  __syncthreads();
  if (wave == 0){
    int w = (lane < 16) ? lds[lane] : 0;
    #pragma unroll
    for (int off=1; off<16; off<<=1){
      int y = __shfl_up(w, off, 64);
      if (lane >= off) w += y;
    }
    if (lane < 16) lds[16+lane] = w;   // inclusive scan of wave totals
  }
  __syncthreads();
  int waveOff = wave ? lds[16+wave-1] : 0;
  return waveOff + x - v;
}

// 64-bit exclusive scan (three 21-bit packed fields; field sums <=16384, no carry)
__device__ unsigned long long block_scan_excl_u64(unsigned long long v,
                                                  unsigned long long* lds, int tid){
  __syncthreads();
  int lane = tid & 63, wave = tid >> 6;
  unsigned long long x = v;
  #pragma unroll
  for (int off=1; off<64; off<<=1){
    unsigned long long y = __shfl_up(x, off, 64);
    if (lane >= off) x += y;
  }
  if (lane == 63) lds[wave] = x;
  __syncthreads();
  if (wave == 0){
    unsigned long long w = (lane < 16) ? lds[lane] : 0ull;
    #pragma unroll
    for (int off=1; off<16; off<<=1){
      unsigned long long y = __shfl_up(w, off, 64);
      if (lane >= off) w += y;
    }
    if (lane < 16) lds[16+lane] = w;
  }
  __syncthreads();
  unsigned long long waveOff = wave ? lds[16+wave-1] : 0ull;
  return waveOff + x - v;
}

// descending-rank pick over a 4096-bin LDS histogram.
// all 1024 threads participate; thread t owns descending positions 4t..4t+3
// (i.e. bins 4095-4t .. 4092-4t). writes sOut = {digit0, rem0, digit1, rem1}.
__device__ void scan_pick4k(const int* __restrict__ hist, int r0, int r1, bool do1,
                            int* lds, int* sOut, int tid){
  int s[4];
  const int d0 = tid*4;
  #pragma unroll
  for (int i=0;i<4;++i) s[i] = hist[4095 - (d0+i)];
  int tot = s[0]+s[1]+s[2]+s[3];
  int c = block_scan_excl(tot, lds, tid);   // count of keys strictly above my segment
  #pragma unroll
  for (int i=0;i<4;++i){
    int nc = c + s[i];
    if (c < r0 && nc >= r0){ sOut[0] = 4095-(d0+i); sOut[1] = r0 - c; }
    if (do1 && c < r1 && nc >= r1){ sOut[2] = 4095-(d0+i); sOut[3] = r1 - c; }
    c = nc;
  }
  __syncthreads();   // sOut visible to all
}

// one block per batch: dual-rank radix select from register-cached keys.
// round 0: 8-bit digit from precomputed gpart partials.
// rounds 1-2: 12-bit digits (8+12+12 = 32 bits), shared 4096-bin hist.
__global__ __launch_bounds__(1024)
void k_select(const unsigned* __restrict__ keys, const int* __restrict__ gpart,
              const int* __restrict__ seq, float* __restrict__ out, int K){
  const int b = blockIdx.x;
  const int tid = threadIdx.x;
  const int lane = tid & 63, wave = tid >> 6;
  __shared__ int part4[4][256];
  __shared__ int histA[4096];       // 4096 bins over 32 banks: ~2-way aliasing = free
  __shared__ int histB[4096];
  __shared__ int lds[32];
  __shared__ unsigned long long ldsL[32];
  __shared__ int smax[16];
  __shared__ int sOut[8];           // [0..3]=A pass, [4..7]=B pass
  __shared__ int sFill;

  int num_keep = seq[b]*2; if (num_keep < 1) num_keep = 1;   // num_keep <= K by construction

  // ---- reduce 64 per-block partials into round-0 histogram (4-way parallel) ----
  {
    int grp = tid >> 8;          // 0..3
    int bin = tid & 255;
    const int* gp = gpart + (b*64 + grp*16)*256 + bin;
    int sum = 0;
    #pragma unroll
    for (int w=0; w<16; ++w) sum += gp[w*256];
    part4[grp][bin] = sum;
  }

  // ---- load 16 consecutive keys per thread into registers (read once) ----
  const unsigned* kb = keys + (size_t)b*NN + tid*16;
  unsigned kk[16];
  #pragma unroll
  for (int q=0;q<4;++q){
    uint4 v = ((const uint4*)kb)[q];
    kk[4*q+0]=v.x; kk[4*q+1]=v.y; kk[4*q+2]=v.z; kk[4*q+3]=v.w;
  }
  __syncthreads();   // part4 ready

  // ---- round 0 from partials: both ranks share the same histogram ----
  int r0 = K, r1 = num_keep;
  int x0 = 0;
  if (tid < 256){
    int bin = 255 - tid;
    x0 = part4[0][bin] + part4[1][bin] + part4[2][bin] + part4[3][bin];
  }
  {
    int pre = block_scan_excl(x0, lds, tid);   // threads >=256 contribute 0
    if (tid < 256){
      int nc = pre + x0;
      if (pre < r0 && nc >= r0){ sOut[0] = 255-tid; sOut[1] = r0-pre; }
      if (pre < r1 && nc >= r1){ sOut[2] = 255-tid; sOut[3] = r1-pre; }
    }
    __syncthreads();
  }
  unsigned pref0 = (unsigned)sOut[0] << 24;  int r0n = sOut[1];
  unsigned pref1 = (unsigned)sOut[2] << 24;  int r1n = sOut[3];
  r0 = r0n; r1 = r1n;
  bool same = (pref0 == pref1);
  unsigned decided = 0xFF000000u;
  __syncthreads();   // sOut consumed

  // ---- rounds 1..2 (12-bit digits): ONE key pass builds A (and B when diverged) ----
  #pragma unroll
  for (int round=0; round<2; ++round){
    const int shift = 12 - 12*round;     // 12, then 0
    #pragma unroll
    for (int i=0;i<4;++i){
      histA[tid + 1024*i] = 0;
      histB[tid + 1024*i] = 0;
    }
    __syncthreads();
    const bool dual = !same;
    #pragma unroll
    for (int j=0;j<16;++j){
      unsigned k = kk[j];
      if (((k ^ pref0) & decided) == 0u)
        atomicAdd(&histA[(k>>shift)&0xFFFu], 1);
      if (dual && ((k ^ pref1) & decided) == 0u)
        atomicAdd(&histB[(k>>shift)&0xFFFu], 1);
    }
    __syncthreads();
    scan_pick4k(histA, r0, r1, same, lds, sOut, tid);
    if (dual) scan_pick4k(histB, r1, 0, false, lds, sOut+4, tid);
    int bin0 = sOut[0], rem0 = sOut[1];
    int bin1 = dual ? sOut[4] : sOut[2];
    int rem1 = dual ? sOut[5] : sOut[3];
    __syncthreads();   // sOut consumed before next round
    pref0 |= (unsigned)bin0 << shift;  r0 = rem0;
    pref1 |= (unsigned)bin1 << shift;  r1 = rem1;
    same = same && (bin0 == bin1);
    decided |= (0xFFFu << shift);
  }
  const unsigned TK = pref0;  const int needK = r0;   // rank-K threshold (descending)
  const unsigned TN = pref1;  const int needN = r1;   // rank-num_keep threshold

  // ---- tie-rank + output-slot offsets: ONE packed 64-bit scan ----
  // oKept closed form: per-thread ties kept = clamp(needN - oTN_t, 0, cTN_t);
  // the prefix of that telescopes to min(needN, oTN). So oKept = oGT + min(needN, oTN).
  int cTK=0, cTN=0, cGT=0;
  #pragma unroll
  for (int j=0;j<16;++j){
    unsigned k = kk[j];
    cTK += (k==TK); cTN += (k==TN); cGT += (k>TN);
  }
  unsigned long long pk = block_scan_excl_u64(
      ((unsigned long long)cTK<<42) | ((unsigned long long)cTN<<21) | (unsigned long long)cGT,
      ldsL, tid);
  const int oTK = (int)(pk>>42);
  const int oTN = (int)((pk>>21) & 0x1FFFFFu);
  const int oGT = (int)(pk & 0x1FFFFFu);
  const int oKept = oGT + min(needN, oTN);

  // ---- fill = max index in the full top-K set ----
  const int base = tid*16;
  int tK=oTK, maxIdx=-1;
  #pragma unroll
  for (int j=0;j<16;++j){
    unsigned k=kk[j];
    bool inK = (k>TK) || ((k==TK) && (tK<needK));  if (k==TK) tK++;
    if (inK) maxIdx = base+j;                 // ascending j -> last wins = max
  }
  int mv=maxIdx;
  #pragma unroll
  for (int off=32; off; off>>=1){
    int y = __shfl_down(mv, off, 64);
    mv = mv > y ? mv : y;
  }
  if (lane==0) smax[wave]=mv;
  __syncthreads();
  if (tid==0){
    int f=-1;
    #pragma unroll
    for (int i=0;i<16;++i) f = f > smax[i] ? f : smax[i];
    sFill = f;
  }
  __syncthreads();
  const int fill = sFill;

  // output layout: [idx BK][emb BKD][scores BK][mask BK], all float32
  float* out_idx = out;
  float* out_sc  = out + (size_t)NB*K + (size_t)NB*K*ND;
  float* out_mk  = out_sc + (size_t)NB*K;
  const int ob = b*K;
  const unsigned kNEG = fkey(NEG_FILL_F);

  int tN2=oTN, p=oKept;
  #pragma unroll
  for (int j=0;j<16;++j){
    unsigned k=kk[j];
    bool kept = (k>TN) || ((k==TN) && (tN2<needN));  if (k==TN) tN2++;
    if (kept){
      int n = base+j;
      out_idx[ob+p] = (float)n;
      out_sc[ob+p]  = fkey_inv(k);
      out_mk[ob+p]  = (k != kNEG) ? 1.0f : 0.0f;
      ++p;
    }
  }
  if (num_keep < K){
    float fs = fkey_inv(keys[(size_t)b*NN + fill]);
    for (int q = num_keep + tid; q < K; q += 1024){
      out_idx[ob+q] = (float)fill;
      out_sc[ob+q]  = fs;
      out_mk[ob+q]  = 0.0f;
    }
  }
}

// out_emb[b,p,:] = embeddings[b, idx[b,p], :]; grid.y = batch, no division
__global__ void k_gather(const float* __restrict__ emb, const float* __restrict__ out_idx,
                         float* __restrict__ out_emb, int K){
  int b = blockIdx.y;
  int g = blockIdx.x*256 + threadIdx.x;   // float4 slot within batch: K*64 slots
  if (g >= K*64) return;
  int c = g & 63;                          // float4 column 0..63
  int p = g >> 6;                          // row within batch
  size_t r = (size_t)b*K + p;
  int idx = (int)out_idx[r];
  const float4* src = (const float4*)(emb + ((size_t)b*NN + (size_t)idx)*ND);
  float4* dst = (float4*)(out_emb + r*(size_t)ND);
  dst[c] = src[c];
}

extern "C" void kernel_launch(void* const* d_in, const int* in_sizes, int n_in,
                              void* d_out, int out_size, void* d_ws, size_t ws_size,
                              hipStream_t stream) {
  const float* emb  = (const float*)d_in[0];
  const float* sa   = (const float*)d_in[1];
  const float* sb   = (const float*)d_in[2];
  const int*   mask = (const int*)d_in[3];
  const int*   seq  = (const int*)d_in[4];
  float* out = (float*)d_out;
  unsigned* ws_keys = (unsigned*)d_ws;            // B*N uints = 512 KB
  int* gpart = (int*)d_ws + (size_t)NB*NN;        // 512 blocks * 256 bins

  int K = out_size / (NB*(ND+3));    // out_size = B*K*(D+3)
  if (K <= 0) return;

  k_scores<<<(NB*NN)/256, 256, 0, stream>>>(sa, sb, mask, ws_keys, gpart);
  k_select<<<NB, 1024, 0, stream>>>(ws_keys, gpart, seq, out, K);
  dim3 ggrid((K*64 + 255)/256, NB);
  k_gather<<<ggrid, 256, 0, stream>>>(emb, out, out + (size_t)NB*K, K);
}